// Round 1
// baseline (878.386 us; speedup 1.0000x reference)
//
#include <hip/hip_runtime.h>

#define NTOT 12288
#define DIM  256
#define NB   2
#define TM   64
#define TN   128
#define BK   32

// ---------- ordered-uint encoding for float atomicMax ----------
__device__ __forceinline__ unsigned toOrd(float f) {
    unsigned u = __float_as_uint(f);
    return (u & 0x80000000u) ? ~u : (u | 0x80000000u);
}
__device__ __forceinline__ float fromOrd(unsigned u) {
    unsigned b = (u & 0x80000000u) ? (u ^ 0x80000000u) : ~u;
    return __uint_as_float(b);
}

// ws layout:
//   [0,16)        int cnts[4]: cnts[0..1] = nval[b], cnts[2..3] = ninv[b]
//   [256, +96KB)  unsigned maxsim[NB*NTOT]   (indexed by compacted buffer row)
//   [98560, +24MB) float buf[NB][NTOT][DIM]  (valid rows from front, invalid from back)

// ---------------- kernel 1: normalize + compact ----------------
__global__ __launch_bounds__(256) void k_norm_compact(
    const float* __restrict__ feat, const int* __restrict__ mask,
    float* __restrict__ buf, unsigned* __restrict__ maxsim, int* __restrict__ cnts)
{
    int tid  = threadIdx.x;
    int wid  = tid >> 6, lane = tid & 63;
    int row  = blockIdx.x * 4 + wid;          // [0, NB*NTOT)
    int b    = row / NTOT;

    const float4 v = reinterpret_cast<const float4*>(feat + (size_t)row * DIM)[lane];
    float ss = v.x*v.x + v.y*v.y + v.z*v.z + v.w*v.w;
    #pragma unroll
    for (int off = 32; off; off >>= 1) ss += __shfl_xor(ss, off);
    float inv = 1.0f / fmaxf(sqrtf(ss), 1e-12f);

    int dest = 0;
    if (lane == 0) {
        int m = mask[row];
        if (m) {
            dest = atomicAdd(&cnts[b], 1);                 // valid: from front
        } else {
            int s = atomicAdd(&cnts[NB + b], 1);           // invalid: from back
            dest = NTOT - 1 - s;
            maxsim[(size_t)b * NTOT + dest] = 0u;          // init (= -NaN, identity for max)
        }
    }
    dest = __shfl(dest, 0);

    float4 o; o.x = v.x*inv; o.y = v.y*inv; o.z = v.z*inv; o.w = v.w*inv;
    reinterpret_cast<float4*>(buf + ((size_t)b * NTOT + dest) * DIM)[lane] = o;
}

// -------- kernel 2: fp32 GEMM (inv rows x val cols), row-max epilogue --------
__global__ __launch_bounds__(256) void k_simmax(
    const float* __restrict__ buf, unsigned* __restrict__ maxsim, const int* __restrict__ cnts)
{
    int b    = blockIdx.z;
    int nval = cnts[b];
    int ninv = cnts[NB + b];
    if ((int)blockIdx.x * TM >= ninv) return;
    if ((int)blockIdx.y * TN >= nval) return;
    int row0 = (NTOT - ninv) + blockIdx.x * TM;   // compacted buffer rows (invalid block)
    int col0 = blockIdx.y * TN;                   // compacted buffer rows (valid block)

    __shared__ __align__(16) float As[BK][68];    // [k][m], pad keeps b128 16B-aligned
    __shared__ __align__(16) float Bs[BK][132];   // [k][n]

    const float* base = buf + (size_t)b * NTOT * DIM;

    int tid = threadIdx.x;
    int tx = tid & 15, ty = tid >> 4;             // 16x16 thread grid; 4 rows x 8 cols each

    float acc[4][8];
    #pragma unroll
    for (int i = 0; i < 4; i++)
        #pragma unroll
        for (int j = 0; j < 8; j++) acc[i][j] = 0.0f;

    for (int kt = 0; kt < DIM; kt += BK) {
        // stage A: 64 rows x 32 k = 512 float4 chunks (2 per thread), transposed into LDS
        #pragma unroll
        for (int j = 0; j < 2; j++) {
            int c = tid + j * 256;
            int r = c >> 3, kk = (c & 7) * 4;
            int rg = row0 + r; if (rg > NTOT - 1) rg = NTOT - 1;
            float4 t4 = reinterpret_cast<const float4*>(base + (size_t)rg * DIM + kt + kk)[0];
            As[kk+0][r] = t4.x; As[kk+1][r] = t4.y; As[kk+2][r] = t4.z; As[kk+3][r] = t4.w;
        }
        // stage B: 128 cols x 32 k = 1024 chunks (4 per thread)
        #pragma unroll
        for (int j = 0; j < 4; j++) {
            int c = tid + j * 256;
            int r = c >> 3, kk = (c & 7) * 4;
            int cg = col0 + r; if (cg > NTOT - 1) cg = NTOT - 1;
            float4 t4 = reinterpret_cast<const float4*>(base + (size_t)cg * DIM + kt + kk)[0];
            Bs[kk+0][r] = t4.x; Bs[kk+1][r] = t4.y; Bs[kk+2][r] = t4.z; Bs[kk+3][r] = t4.w;
        }
        __syncthreads();
        #pragma unroll
        for (int k = 0; k < BK; k++) {
            float4 a4  = *reinterpret_cast<const float4*>(&As[k][ty*4]);
            float4 b4a = *reinterpret_cast<const float4*>(&Bs[k][tx*8]);
            float4 b4b = *reinterpret_cast<const float4*>(&Bs[k][tx*8+4]);
            float av[4] = {a4.x, a4.y, a4.z, a4.w};
            float bv[8] = {b4a.x, b4a.y, b4a.z, b4a.w, b4b.x, b4b.y, b4b.z, b4b.w};
            #pragma unroll
            for (int i = 0; i < 4; i++)
                #pragma unroll
                for (int j = 0; j < 8; j++)
                    acc[i][j] = fmaf(av[i], bv[j], acc[i][j]);
        }
        __syncthreads();
    }

    // epilogue: per-row max over this block's 128 cols, reduce across the 16 tx lanes
    #pragma unroll
    for (int i = 0; i < 4; i++) {
        int rg = row0 + ty * 4 + i;
        float m = -INFINITY;
        #pragma unroll
        for (int j = 0; j < 8; j++) {
            int cg = col0 + tx * 8 + j;
            if (cg < nval) m = fmaxf(m, acc[i][j]);
        }
        #pragma unroll
        for (int off = 1; off < 16; off <<= 1) m = fmaxf(m, __shfl_xor(m, off));
        if (tx == 0 && rg < NTOT)
            atomicMax(maxsim + (size_t)b * NTOT + rg, toOrd(m));
    }
}

// ---------------- kernel 3: finalize scalar ----------------
__global__ __launch_bounds__(256) void k_final(
    const unsigned* __restrict__ maxsim, const int* __restrict__ cnts, float* __restrict__ out)
{
    __shared__ float ssum[NB];
    __shared__ int   scnt[NB];
    int tid = threadIdx.x;
    if (tid < NB) { ssum[tid] = 0.0f; scnt[tid] = 0; }
    __syncthreads();

    for (int b = 0; b < NB; b++) {
        int ninv = cnts[NB + b];
        float ls = 0.0f; int lc = 0;
        for (int i = tid; i < ninv; i += 256) {
            int r = NTOT - ninv + i;
            float ms = fromOrd(maxsim[(size_t)b * NTOT + r]);
            if (ms > 0.8f) { ls += 1.0f - ms; lc++; }      // NaN-safe: NaN>0.8 is false
        }
        #pragma unroll
        for (int off = 32; off; off >>= 1) {
            ls += __shfl_xor(ls, off);
            lc += __shfl_xor(lc, off);
        }
        if ((tid & 63) == 0) { atomicAdd(&ssum[b], ls); atomicAdd(&scnt[b], lc); }
    }
    __syncthreads();

    if (tid == 0) {
        float tl = 0.0f, tp = 0.0f;
        for (int b = 0; b < NB; b++) {
            int nval = cnts[b], ninv = cnts[NB + b], nc = scnt[b];
            bool active = (nc > 0) && (nval > 0) && (ninv > 0);
            if (active) {
                float pseudo = ssum[b] / (float)(nc > 0 ? nc : 1);
                tl += pseudo * (float)ninv;
                tp += (float)ninv;
            }
        }
        out[0] = (tp > 0.0f) ? (0.01f * tl / tp) : 0.0f;
    }
}

extern "C" void kernel_launch(void* const* d_in, const int* in_sizes, int n_in,
                              void* d_out, int out_size, void* d_ws, size_t ws_size,
                              hipStream_t stream)
{
    const float* feat = (const float*)d_in[0];
    const int*   mask = (const int*)d_in[1];

    char* ws = (char*)d_ws;
    int*      cnts   = (int*)ws;
    unsigned* maxsim = (unsigned*)(ws + 256);
    float*    buf    = (float*)(ws + 98560);   // 256 + NB*NTOT*4 rounded; 16B-aligned

    hipMemsetAsync(d_ws, 0, 256, stream);      // zero counters (ws is poisoned each call)

    hipLaunchKernelGGL(k_norm_compact, dim3(NB * NTOT / 4), dim3(256), 0, stream,
                       feat, mask, buf, maxsim, cnts);
    hipLaunchKernelGGL(k_simmax, dim3(NTOT / TM, NTOT / TN, NB), dim3(256), 0, stream,
                       buf, maxsim, cnts);
    hipLaunchKernelGGL(k_final, dim3(1), dim3(256), 0, stream,
                       maxsim, cnts, (float*)d_out);
}

// Round 2
// 317.896 us; speedup vs baseline: 2.7631x; 2.7631x over previous
//
#include <hip/hip_runtime.h>

#define NTOT 12288
#define DIM  256
#define NB   2
#define TM_  128
#define TN_  128
#define TK_  64

typedef __attribute__((ext_vector_type(8))) short bf16x8;
typedef __attribute__((ext_vector_type(16))) float f32x16;

// ---------- ordered-uint encoding for float atomicMax ----------
__device__ __forceinline__ unsigned toOrd(float f) {
    unsigned u = __float_as_uint(f);
    return (u & 0x80000000u) ? ~u : (u | 0x80000000u);
}
__device__ __forceinline__ float fromOrd(unsigned u) {
    unsigned b = (u & 0x80000000u) ? (u ^ 0x80000000u) : ~u;
    return __uint_as_float(b);
}
__device__ __forceinline__ ushort f2bf(float x) {          // RNE float->bf16
    unsigned u = __float_as_uint(x);
    unsigned r = (u + 0x7FFFu + ((u >> 16) & 1u)) >> 16;
    return (ushort)r;
}
__device__ __forceinline__ float bf2f(ushort h) { return __uint_as_float(((unsigned)h) << 16); }

__device__ __forceinline__ void load_lds16(const void* g, void* l) {
    __builtin_amdgcn_global_load_lds(
        (const __attribute__((address_space(1))) unsigned int*)g,
        (__attribute__((address_space(3))) unsigned int*)l, 16, 0, 0);
}

// ws layout:
//   [0,64)                      int cnts[4]: [0..1]=nval[b], [2..3]=ninv[b]
//   [64, 64+96KB)               dest[NB*NTOT] ints  -- ALIASED later as unsigned maxsim[]
//   [98368, +12.58MB)           hi plane  ushort[NB][NTOT][DIM]
//   [12681280, +12.58MB)        lo plane  ushort[NB][NTOT][DIM]

// ---------------- kernel 1: per-batch prefix scan -> destinations ----------------
__global__ __launch_bounds__(256) void k_scan(
    const int* __restrict__ mask, int* __restrict__ dest, int* __restrict__ cnts)
{
    int b = blockIdx.x;
    int tid = threadIdx.x;
    int lane = tid & 63, w = tid >> 6;
    __shared__ int wsum[4];
    int running = 0;
    for (int c0 = 0; c0 < NTOT; c0 += 256) {
        int i = c0 + tid;
        int m = mask[b * NTOT + i] ? 1 : 0;
        int v = m;
        #pragma unroll
        for (int off = 1; off < 64; off <<= 1) {
            int t = __shfl_up(v, off);
            if (lane >= off) v += t;
        }
        if (lane == 63) wsum[w] = v;
        __syncthreads();
        int woff = 0;
        #pragma unroll
        for (int k = 0; k < 4; k++) if (k < w) woff += wsum[k];
        int chunk_total = wsum[0] + wsum[1] + wsum[2] + wsum[3];
        int ex = running + woff + v - m;          // exclusive prefix of "valid"
        int d = m ? ex : (NTOT - 1 - (i - ex));   // invalid packed from the back
        dest[b * NTOT + i] = d;
        running += chunk_total;
        __syncthreads();
    }
    if (tid == 0) { cnts[b] = running; cnts[NB + b] = NTOT - running; }
}

// ---------------- kernel 2: normalize + compact into bf16 hi/lo planes ----------------
__global__ __launch_bounds__(256) void k_norm(
    const float* __restrict__ feat, const int* __restrict__ dest,
    ushort* __restrict__ hi, ushort* __restrict__ lo)
{
    int tid = threadIdx.x;
    int w = tid >> 6, lane = tid & 63;
    int row = blockIdx.x * 4 + w;                 // [0, NB*NTOT)
    int b = row / NTOT;

    const float4 v = reinterpret_cast<const float4*>(feat + (size_t)row * DIM)[lane];
    float ss = v.x * v.x + v.y * v.y + v.z * v.z + v.w * v.w;
    #pragma unroll
    for (int off = 32; off; off >>= 1) ss += __shfl_xor(ss, off);
    float inv = 1.0f / fmaxf(sqrtf(ss), 1e-12f);

    int d = dest[row];
    float x[4] = {v.x * inv, v.y * inv, v.z * inv, v.w * inv};
    ushort4 h4, l4;
    ushort* hp = (ushort*)&h4; ushort* lp = (ushort*)&l4;
    #pragma unroll
    for (int j = 0; j < 4; j++) {
        ushort h = f2bf(x[j]);
        hp[j] = h;
        lp[j] = f2bf(x[j] - bf2f(h));
    }
    size_t base = ((size_t)(b * NTOT + d)) * DIM;
    reinterpret_cast<ushort4*>(hi + base)[lane] = h4;
    reinterpret_cast<ushort4*>(lo + base)[lane] = l4;
}

// -------- kernel 3: MFMA GEMM (inv rows x val cols), bf16x3 split, row-max epilogue --------
__global__ __launch_bounds__(256) void k_simmax_mfma(
    const ushort* __restrict__ hi, const ushort* __restrict__ lo,
    unsigned* __restrict__ maxsim, const int* __restrict__ cnts)
{
    int b = blockIdx.z;
    int nval = cnts[b];
    int ninv = cnts[NB + b];
    if ((int)blockIdx.x * TM_ >= ninv) return;
    if ((int)blockIdx.y * TN_ >= nval) return;
    int rowA0 = (NTOT - ninv) + blockIdx.x * TM_;  // compacted invalid rows
    int col0  = blockIdx.y * TN_;                  // compacted valid rows

    // 4 tiles of 128x64 bf16, 16KB each: A_hi, A_lo, B_hi, B_lo (XOR-swizzled)
    __shared__ __align__(16) ushort ldsbuf[4 * 8192];

    int tid = threadIdx.x;
    int lane = tid & 63, w = tid >> 6;
    int wr = w >> 1, wc = w & 1;
    const size_t pb = (size_t)b * NTOT * DIM;

    f32x16 acc[2][2] = {};

    for (int kt = 0; kt < DIM; kt += TK_) {
        // ---- stage 4 tiles via global_load_lds (linear dest, pre-swizzled source) ----
        #pragma unroll
        for (int t = 0; t < 4; t++) {
            const ushort* plane = (t & 1) ? lo : hi;
            int rbase = (t < 2) ? rowA0 : col0;
            #pragma unroll
            for (int j = 0; j < 4; j++) {
                int cb = (j * 4 + w) * 64;             // wave-uniform chunk base
                int c  = cb + lane;
                int r  = c >> 3;                        // tile row (8 chunks/row)
                int sb = ((c & 7) * 16) ^ ((r & 7) << 4);   // swizzled byte-in-row
                int rg = rbase + r; if (rg > NTOT - 1) rg = NTOT - 1;
                const char* g = (const char*)(plane + pb + (size_t)rg * DIM + kt) + sb;
                load_lds16(g, (char*)(ldsbuf + t * 8192) + cb * 16);
            }
        }
        __syncthreads();

        // ---- compute: 4 k-quads x (2x2 tiles) x 3 passes = 48 MFMA ----
        #pragma unroll
        for (int kq = 0; kq < 4; kq++) {
            int kb = kq * 32 + (lane >> 5) * 16;       // byte offset along K
            bf16x8 aH[2], aL[2], bH[2], bL[2];
            #pragma unroll
            for (int mt = 0; mt < 2; mt++) {
                int r = wr * 64 + mt * 32 + (lane & 31);
                int off = (r * 128 + kb) ^ ((r & 7) << 4);
                aH[mt] = *(const bf16x8*)((const char*)ldsbuf + 0 * 16384 + off);
                aL[mt] = *(const bf16x8*)((const char*)ldsbuf + 1 * 16384 + off);
            }
            #pragma unroll
            for (int nt = 0; nt < 2; nt++) {
                int r = wc * 64 + nt * 32 + (lane & 31);
                int off = (r * 128 + kb) ^ ((r & 7) << 4);
                bH[nt] = *(const bf16x8*)((const char*)ldsbuf + 2 * 16384 + off);
                bL[nt] = *(const bf16x8*)((const char*)ldsbuf + 3 * 16384 + off);
            }
            #pragma unroll
            for (int mt = 0; mt < 2; mt++)
                #pragma unroll
                for (int nt = 0; nt < 2; nt++) {
                    acc[mt][nt] = __builtin_amdgcn_mfma_f32_32x32x16_bf16(aH[mt], bH[nt], acc[mt][nt], 0, 0, 0);
                    acc[mt][nt] = __builtin_amdgcn_mfma_f32_32x32x16_bf16(aH[mt], bL[nt], acc[mt][nt], 0, 0, 0);
                    acc[mt][nt] = __builtin_amdgcn_mfma_f32_32x32x16_bf16(aL[mt], bH[nt], acc[mt][nt], 0, 0, 0);
                }
        }
        __syncthreads();
    }

    // ---- epilogue: per-row max, mask cols >= nval, butterfly over 32 cols ----
    int hhalf = lane >> 5;
    int cl = lane & 31;
    #pragma unroll
    for (int mt = 0; mt < 2; mt++) {
        float mrow[16];
        int cg0 = col0 + wc * 64 + cl;
        int cg1 = cg0 + 32;
        bool v0 = cg0 < nval, v1 = cg1 < nval;
        #pragma unroll
        for (int rr = 0; rr < 16; rr++) {
            float a0 = v0 ? acc[mt][0][rr] : -INFINITY;
            float a1 = v1 ? acc[mt][1][rr] : -INFINITY;
            mrow[rr] = fmaxf(a0, a1);
        }
        #pragma unroll
        for (int off = 1; off <= 16; off <<= 1)
            #pragma unroll
            for (int rr = 0; rr < 16; rr++)
                mrow[rr] = fmaxf(mrow[rr], __shfl_xor(mrow[rr], off));
        if (cl == 0) {
            #pragma unroll
            for (int rr = 0; rr < 16; rr++) {
                int rowg = rowA0 + wr * 64 + mt * 32 + (rr & 3) + 8 * (rr >> 2) + 4 * hhalf;
                if (rowg < NTOT)
                    atomicMax(maxsim + (size_t)b * NTOT + rowg, toOrd(mrow[rr]));
            }
        }
    }
}

// ---------------- kernel 4: finalize scalar ----------------
__global__ __launch_bounds__(256) void k_final(
    const unsigned* __restrict__ maxsim, const int* __restrict__ cnts, float* __restrict__ out)
{
    __shared__ float ssum[NB];
    __shared__ int   scnt[NB];
    int tid = threadIdx.x;
    if (tid < NB) { ssum[tid] = 0.0f; scnt[tid] = 0; }
    __syncthreads();

    for (int b = 0; b < NB; b++) {
        int ninv = cnts[NB + b];
        float ls = 0.0f; int lc = 0;
        for (int i = tid; i < ninv; i += 256) {
            int r = NTOT - ninv + i;
            float ms = fromOrd(maxsim[(size_t)b * NTOT + r]);
            if (ms > 0.8f) { ls += 1.0f - ms; lc++; }   // NaN-safe
        }
        #pragma unroll
        for (int off = 32; off; off >>= 1) {
            ls += __shfl_xor(ls, off);
            lc += __shfl_xor(lc, off);
        }
        if ((tid & 63) == 0) { atomicAdd(&ssum[b], ls); atomicAdd(&scnt[b], lc); }
    }
    __syncthreads();

    if (tid == 0) {
        float tl = 0.0f, tp = 0.0f;
        for (int b = 0; b < NB; b++) {
            int nval = cnts[b], ninv = cnts[NB + b], nc = scnt[b];
            bool active = (nc > 0) && (nval > 0) && (ninv > 0);
            if (active) {
                float pseudo = ssum[b] / (float)(nc > 0 ? nc : 1);
                tl += pseudo * (float)ninv;
                tp += (float)ninv;
            }
        }
        out[0] = (tp > 0.0f) ? (0.01f * tl / tp) : 0.0f;
    }
}

extern "C" void kernel_launch(void* const* d_in, const int* in_sizes, int n_in,
                              void* d_out, int out_size, void* d_ws, size_t ws_size,
                              hipStream_t stream)
{
    const float* feat = (const float*)d_in[0];
    const int*   mask = (const int*)d_in[1];

    char* ws = (char*)d_ws;
    int*      cnts   = (int*)ws;
    int*      dest   = (int*)(ws + 64);
    unsigned* maxsim = (unsigned*)(ws + 64);               // aliases dest (sequenced)
    ushort*   hi     = (ushort*)(ws + 98368);
    ushort*   lo     = (ushort*)(ws + 98368 + (size_t)NB * NTOT * DIM * 2);

    hipLaunchKernelGGL(k_scan, dim3(NB), dim3(256), 0, stream, mask, dest, cnts);
    hipLaunchKernelGGL(k_norm, dim3(NB * NTOT / 4), dim3(256), 0, stream, feat, dest, hi, lo);
    hipMemsetAsync(maxsim, 0, (size_t)NB * NTOT * 4, stream);   // dest no longer needed
    hipLaunchKernelGGL(k_simmax_mfma, dim3(NTOT / TM_, NTOT / TN_, NB), dim3(256), 0, stream,
                       hi, lo, maxsim, cnts);
    hipLaunchKernelGGL(k_final, dim3(1), dim3(256), 0, stream, maxsim, cnts, (float*)d_out);
}